// Round 4
// baseline (312.587 us; speedup 1.0000x reference)
//
#include <hip/hip_runtime.h>

// SmoothQuant linear, M=32768, K=1024, N=1024.
// colmax partials (x) -> fused stage2(x)+colmax(w) -> finalize scales
// -> fused wave-per-row int8 quant (w then x) -> i8 MFMA GEMM
// (256x256 tile, BK=128, 8-phase counted-vmcnt pipeline, 32x32x32 MFMA,
//  bank-free LDS swizzle) + dequant epilogue.

typedef int v4i  __attribute__((ext_vector_type(4)));
typedef int v16i __attribute__((ext_vector_type(16)));

__device__ __forceinline__ void gld_lds16(const void* g, void* l) {
    __builtin_amdgcn_global_load_lds(
        (const __attribute__((address_space(1))) void*)g,
        (__attribute__((address_space(3))) void*)l,
        16, 0, 0);
}

// ---- column abs-max over a row range: out[k] = max_{r in [r0,r1)} |src[r][k]| ------
__device__ __forceinline__ void colmax_body(const float* __restrict__ src,
                                            int r0, int r1, int K,
                                            float* __restrict__ dst) {
    const int c = threadIdx.x * 4;          // 256 threads cover K=1024
    float m0 = 0.f, m1 = 0.f, m2 = 0.f, m3 = 0.f;
    const float* p = src + (size_t)r0 * K + c;
#pragma unroll 8
    for (int r = r0; r < r1; ++r, p += K) {
        float4 v = *(const float4*)p;
        m0 = fmaxf(m0, fabsf(v.x));
        m1 = fmaxf(m1, fabsf(v.y));
        m2 = fmaxf(m2, fabsf(v.z));
        m3 = fmaxf(m3, fabsf(v.w));
    }
    float4 o; o.x = m0; o.y = m1; o.z = m2; o.w = m3;
    *(float4*)(dst + c) = o;
}

// ---- stage-1 col abs-max of x: 512 blocks x 64 rows --------------------------------
__global__ __launch_bounds__(256) void colmax_part_kernel(const float* __restrict__ src,
                                                          int rows, int rpb, int K,
                                                          float* __restrict__ partial) {
    int r0 = blockIdx.x * rpb;
    int r1 = r0 + rpb; if (r1 > rows) r1 = rows;
    colmax_body(src, r0, r1, K, partial + (size_t)blockIdx.x * K);
}

// ---- fused stage-2: blocks [0,16) reduce x-partials -> p2x; [16,32) colmax(w) -> pw -
__global__ __launch_bounds__(256) void part2_fused_kernel(const float* __restrict__ p1x, int nx,
                                                          const float* __restrict__ w, int nw,
                                                          float* __restrict__ p2x,
                                                          float* __restrict__ pw, int K) {
    const int b = blockIdx.x;
    if (b < 16) {
        const int rpb = nx >> 4;
        colmax_body(p1x, b * rpb, (b + 1) * rpb, K, p2x + (size_t)b * K);
    } else {
        const int rpb = nw >> 4;
        colmax_body(w, (b - 16) * rpb, (b - 15) * rpb, K, pw + (size_t)(b - 16) * K);
    }
}

// ---- finalize: smooth = sqrt(max(mx*mw, eps)); inv = 1/smooth (IEEE) ----------------
__global__ void finalize_kernel(const float* __restrict__ px, int nx,
                                const float* __restrict__ pw, int nw,
                                float* __restrict__ smooth, float* __restrict__ inv_s, int K) {
    int c = blockIdx.x * blockDim.x + threadIdx.x;
    if (c >= K) return;
    float mx = 0.f, mw = 0.f;
    for (int r = 0; r < nx; ++r) mx = fmaxf(mx, px[(size_t)r * K + c]);
    for (int r = 0; r < nw; ++r) mw = fmaxf(mw, pw[(size_t)r * K + c]);
    float s = sqrtf(fmaxf(mx * mw, 1e-12f));
    smooth[c] = s;
    inv_s[c]  = 1.0f / s;
}

// ---- wave-per-row int8 quant body: 16 contiguous cols per lane, one dwordx4 store ---
__device__ __forceinline__ void quant_row_body(const float* __restrict__ src,
                                               const float* __restrict__ colscale,
                                               signed char* __restrict__ q,
                                               float* __restrict__ rowscale,
                                               int row, int K, int lane) {
    const float* srow = src + (size_t)row * K + lane * 16;
    const float* crow = colscale + lane * 16;
    float xs[16];
    float mv = 0.f;
#pragma unroll
    for (int i = 0; i < 4; ++i) {
        float4 v  = *(const float4*)(srow + i * 4);
        float4 cs = *(const float4*)(crow + i * 4);
        xs[i*4+0] = v.x * cs.x; xs[i*4+1] = v.y * cs.y;
        xs[i*4+2] = v.z * cs.z; xs[i*4+3] = v.w * cs.w;
        mv = fmaxf(mv, fmaxf(fmaxf(fabsf(xs[i*4+0]), fabsf(xs[i*4+1])),
                             fmaxf(fabsf(xs[i*4+2]), fabsf(xs[i*4+3]))));
    }
#pragma unroll
    for (int off = 32; off > 0; off >>= 1)
        mv = fmaxf(mv, __shfl_xor(mv, off, 64));
    const float rs = fmaxf(mv / 127.0f, 1e-12f);   // IEEE divide, matches numpy
    unsigned pk[4];
#pragma unroll
    for (int i = 0; i < 4; ++i) {
        float q0 = fminf(fmaxf(rintf(xs[i*4+0] / rs), -127.f), 127.f);  // IEEE divides
        float q1 = fminf(fmaxf(rintf(xs[i*4+1] / rs), -127.f), 127.f);
        float q2 = fminf(fmaxf(rintf(xs[i*4+2] / rs), -127.f), 127.f);
        float q3 = fminf(fmaxf(rintf(xs[i*4+3] / rs), -127.f), 127.f);
        int b0 = (int)q0, b1 = (int)q1, b2 = (int)q2, b3 = (int)q3;
        pk[i] = (unsigned)(b0 & 0xff) | ((unsigned)(b1 & 0xff) << 8)
              | ((unsigned)(b2 & 0xff) << 16) | ((unsigned)(b3 & 0xff) << 24);
    }
    *(uint4*)(q + (size_t)row * K + lane * 16) = make_uint4(pk[0], pk[1], pk[2], pk[3]);
    if (lane == 0) rowscale[row] = rs;
}

// ---- fused quant: blocks [0, N/4) quantize w; blocks [N/4, N/4+M/4) quantize x ------
__global__ __launch_bounds__(256) void quant_fused_kernel(
    const float* __restrict__ w, const float* __restrict__ x,
    const float* __restrict__ smooth, const float* __restrict__ inv_s,
    signed char* __restrict__ w_q, float* __restrict__ w_s,
    signed char* __restrict__ x_q, float* __restrict__ x_s,
    int K, int wblocks) {
    const int wave = threadIdx.x >> 6, lane = threadIdx.x & 63;
    const int b = blockIdx.x;
    if (b < wblocks) {
        quant_row_body(w, smooth, w_q, w_s, b * 4 + wave, K, lane);
    } else {
        quant_row_body(x, inv_s, x_q, x_s, (b - wblocks) * 4 + wave, K, lane);
    }
}

// ---- i8 GEMM: out[m,n] = i32acc * x_s[m] * w_s[n] + bias[n] -------------------------
// 256x256 tile, BK=128, 8 waves (2Mx4N, each 128x64 out = 4x2 tiles of 32x32),
// 8-phase counted-vmcnt pipeline (T3+T4), bank-free XOR-swizzled LDS (T2),
// setprio around MFMA (T5), XCD swizzle (T1). MFMA: v_mfma_i32_32x32x32_i8
// (half the instruction count of 16x16x64 for the same ops; 4404 vs 3944 TOPS ubench).
// LDS layout per matrix: [2 buf][2 kslice][256 rows][64 B]; kslice (64B) = 2 ksteps
// of K=32; chunk = kstep*2 + (lane>>5). Swizzle: slot = chunk ^ ((row>>1)&3).
// Bank audit (quarter-wave, 16 lanes): window = 16*(row&1) + 4*slot -> 8 windows x
// 2 lanes = 2-way = free (m136; 16x16 variant measured SQ_LDS_BANK_CONFLICT = 0).
// Staging/phase/vmcnt queue byte-identical to the R3 harness-verified version.
__global__ __launch_bounds__(512, 2) void gemm_i8_kernel(
    const signed char* __restrict__ Aq,   // [M,K]
    const signed char* __restrict__ Bq,   // [N,K]
    const float* __restrict__ xs,         // [M]
    const float* __restrict__ wsc,        // [N]
    const float* __restrict__ bias,       // [N]
    float* __restrict__ out,              // [M,N] f32
    int M, int N, int K) {
    __shared__ __align__(16) signed char As[65536];   // [2][2][256*64]
    __shared__ __align__(16) signed char Bs[65536];

    const int tid  = threadIdx.x;
    const int lane = tid & 63;
    const int wave = tid >> 6;
    const int wm = wave >> 2;             // 0..1 -> rows wm*128..+127
    const int wn = wave & 3;              // 0..3 -> cols wn*64..+63
    const int lrow = lane & 31;           // row within a 32x32 tile
    const int hi   = lane >> 5;           // k-half within a 32-k step

    const int NT = K >> 7;                // K/128 tiles (8 for K=1024)

    // XCD-aware bijective swizzle (grid % 8 == 0): each XCD gets contiguous wg chunk.
    const int nwg = gridDim.x;
    const int wg  = (blockIdx.x & 7) * (nwg >> 3) + (blockIdx.x >> 3);
    const int nTn = N >> 8;
    const int tm = wg / nTn, tn = wg % nTn;
    const int bm = tm << 8, bn = tn << 8;

    // staging: thread t -> LDS slot (row=t>>2, chunk=t&3); global chunk = chunk^((row>>1)&3)
    const int srow = tid >> 2;            // 0..127 (second load adds 128 rows, same (row>>1)&3)
    const int schk = (tid & 3) ^ ((tid >> 3) & 3);
    const signed char* srcA0 = Aq + (size_t)(bm + srow) * K + schk * 16;
    const signed char* srcA1 = srcA0 + (size_t)128 * K;
    const signed char* srcB0 = Bq + (size_t)(bn + srow) * K + schk * 16;
    const signed char* srcB1 = srcB0 + (size_t)128 * K;
    const int ldsSt = tid * 16;

    // fragment reads: row = tilebase + lrow; slot = (k'*2+hi) ^ ((lrow>>1)&3)
    const int rsw  = (lrow >> 1) & 3;
    const int swz0 = (hi ^ rsw) * 16;                 // k'=0 chunk slot byte offset
    // k'=1 slot = swz0 ^ 32 (chunk XOR 2)
    const int aOff = (wm * 128 + lrow) * 64;          // + mt*2048
    const int bOff = (wn * 64 + lrow) * 64;           // + nt*2048

    v16i acc[4][2] = {};
    v4i bf[2][2];                                     // [nt][k'] persists MH=0 -> MH=1

#define STAGE_A(T, KS) do { \
        const int go_ = (T) * 128 + (KS) * 64; \
        signed char* l_ = &As[((T) & 1) * 32768 + (KS) * 16384 + ldsSt]; \
        gld_lds16(srcA0 + go_, l_); \
        gld_lds16(srcA1 + go_, l_ + 8192); \
    } while (0)
#define STAGE_B(T, KS) do { \
        const int go_ = (T) * 128 + (KS) * 64; \
        signed char* l_ = &Bs[((T) & 1) * 32768 + (KS) * 16384 + ldsSt]; \
        gld_lds16(srcB0 + go_, l_); \
        gld_lds16(srcB1 + go_, l_ + 8192); \
    } while (0)

// phase: ds_reads -> stage issue -> vmcnt(counted) -> barrier -> lgkm(0) -> 8 MFMA -> barrier
#define PHASE(BUF, KS, MH, STG, WAIT) \
    do { \
        const int hb_ = (BUF) * 32768 + (KS) * 16384; \
        v4i af[2][2]; \
        _Pragma("unroll") \
        for (int mt = 0; mt < 2; ++mt) { \
            af[mt][0] = *(const v4i*)&As[hb_ + aOff + ((MH) * 2 + mt) * 2048 + swz0]; \
            af[mt][1] = *(const v4i*)&As[hb_ + aOff + ((MH) * 2 + mt) * 2048 + (swz0 ^ 32)]; \
        } \
        if ((MH) == 0) { \
            _Pragma("unroll") \
            for (int nt = 0; nt < 2; ++nt) { \
                bf[nt][0] = *(const v4i*)&Bs[hb_ + bOff + nt * 2048 + swz0]; \
                bf[nt][1] = *(const v4i*)&Bs[hb_ + bOff + nt * 2048 + (swz0 ^ 32)]; \
            } \
        } \
        STG; \
        asm volatile("s_waitcnt " WAIT ::: "memory"); \
        asm volatile("s_barrier" ::: "memory"); \
        asm volatile("s_waitcnt lgkmcnt(0)" ::: "memory"); \
        __builtin_amdgcn_sched_barrier(0); \
        __builtin_amdgcn_s_setprio(1); \
        _Pragma("unroll") \
        for (int kk = 0; kk < 2; ++kk) \
            _Pragma("unroll") \
            for (int mt = 0; mt < 2; ++mt) \
                _Pragma("unroll") \
                for (int nt = 0; nt < 2; ++nt) \
                    acc[(MH) * 2 + mt][nt] = __builtin_amdgcn_mfma_i32_32x32x32_i8( \
                        af[mt][kk], bf[nt][kk], acc[(MH) * 2 + mt][nt], 0, 0, 0); \
        __builtin_amdgcn_s_setprio(0); \
        asm volatile("s_barrier" ::: "memory"); \
    } while (0)

    // prologue: tile0 complete + tile1 ks0 (6 halves, 12 loads); wait tile0 landed.
    STAGE_A(0, 0); STAGE_B(0, 0);
    STAGE_A(0, 1); STAGE_B(0, 1);
    STAGE_A(1, 0); STAGE_B(1, 0);
    asm volatile("s_waitcnt vmcnt(4)" ::: "memory");
    asm volatile("s_barrier" ::: "memory");

    // steady state (t = 0 .. NT-3): stage ks1(t+1) in ph1/ph2, ks0(t+2) in ph3/ph4.
    for (int t = 0; t < NT - 2; ++t) {
        const int buf = t & 1;
        PHASE(buf, 0, 0, STAGE_A(t + 1, 1), "vmcnt(8)");
        PHASE(buf, 0, 1, STAGE_B(t + 1, 1), "vmcnt(8)");
        PHASE(buf, 1, 0, STAGE_A(t + 2, 0), "vmcnt(8)");
        PHASE(buf, 1, 1, STAGE_B(t + 2, 0), "vmcnt(8)");
    }
    {   // tile NT-2: last ks1 staging; drain to 4 so ks0(NT-1) is landed.
        const int t = NT - 2, buf = t & 1;
        PHASE(buf, 0, 0, STAGE_A(t + 1, 1), "vmcnt(8)");
        PHASE(buf, 0, 1, STAGE_B(t + 1, 1), "vmcnt(8)");
        PHASE(buf, 1, 0, (void)0, "vmcnt(8)");
        PHASE(buf, 1, 1, (void)0, "vmcnt(4)");
    }
    {   // tile NT-1: drain remaining (ks1(NT-1)) before its read phases.
        const int buf = (NT - 1) & 1;
        PHASE(buf, 0, 0, (void)0, "vmcnt(4)");
        PHASE(buf, 0, 1, (void)0, "vmcnt(0)");
        PHASE(buf, 1, 0, (void)0, "vmcnt(0)");
        PHASE(buf, 1, 1, (void)0, "vmcnt(0)");
    }
#undef PHASE
#undef STAGE_A
#undef STAGE_B

    // epilogue: 32x32 C/D layout col=lane&31, row=(reg&3)+8*(reg>>2)+4*(lane>>5)
    const int ocol0 = bn + wn * 64 + lrow;
    float wv[2], bvv[2];
#pragma unroll
    for (int nt = 0; nt < 2; ++nt) {
        wv[nt]  = wsc[ocol0 + nt * 32];
        bvv[nt] = bias[ocol0 + nt * 32];
    }
#pragma unroll
    for (int mt = 0; mt < 4; ++mt) {
        const int rbase = bm + wm * 128 + mt * 32 + 4 * hi;
#pragma unroll
        for (int r = 0; r < 16; ++r) {
            const int row = rbase + (r & 3) + 8 * (r >> 2);
            const float xv = xs[row];
            float* op = out + (size_t)row * N + ocol0;
            op[0]  = (float)acc[mt][0][r] * xv * wv[0] + bvv[0];
            op[32] = (float)acc[mt][1][r] * xv * wv[1] + bvv[1];
        }
    }
}

extern "C" void kernel_launch(void* const* d_in, const int* in_sizes, int n_in,
                              void* d_out, int out_size, void* d_ws, size_t ws_size,
                              hipStream_t stream) {
    const float* x    = (const float*)d_in[0];
    const float* w    = (const float*)d_in[1];
    const float* bias = (const float*)d_in[2];
    float* out = (float*)d_out;

    const int N = in_sizes[2];            // 1024
    const int K = in_sizes[1] / N;        // 1024
    const int M = in_sizes[0] / K;        // 32768

    char* ws = (char*)d_ws;
    float* p1x       = (float*)(ws);                    // 512 x K   (2 MB)
    float* p2x       = (float*)(ws + 2097152);          // 16 x K    (64 KB)
    float* pw        = (float*)(ws + 2162688);          // 16 x K    (64 KB)
    float* smooth    = (float*)(ws + 2228224);          // K
    float* inv_s     = (float*)(ws + 2232320);          // K
    float* w_s       = (float*)(ws + 2236416);          // N
    float* x_s       = (float*)(ws + 2240512);          // M  (128 KB)
    signed char* x_q = (signed char*)(ws + 2371584);    // M*K (32 MB)
    signed char* w_q = x_q + (size_t)M * K;             // N*K (1 MB)

    // stage-1 col abs-max of x: 512 blocks x 64 rows
    colmax_part_kernel<<<512, 256, 0, stream>>>(x, M, 64, K, p1x);
    // fused stage-2 (x partials) + col abs-max of w: 32 blocks
    part2_fused_kernel<<<32, 256, 0, stream>>>(p1x, 512, w, N, p2x, pw, K);
    // smooth scales
    finalize_kernel<<<(K + 255) / 256, 256, 0, stream>>>(p2x, 16, pw, 16, smooth, inv_s, K);
    // fused quant: w rows then x rows, one wave per row
    quant_fused_kernel<<<N / 4 + M / 4, 256, 0, stream>>>(w, x, smooth, inv_s,
                                                          w_q, w_s, x_q, x_s, K, N / 4);
    // GEMM: 256x256 tiles, 512 threads, grid = 128*4 = 512 (divisible by 8 XCDs)
    gemm_i8_kernel<<<(M / 256) * (N / 256), 512, 0, stream>>>(x_q, w_q, x_s, w_s, bias, out, M, N, K);
}

// Round 5
// 304.656 us; speedup vs baseline: 1.0260x; 1.0260x over previous
//
#include <hip/hip_runtime.h>

// SmoothQuant linear, M=32768, K=1024, N=1024.
// colmax partials (x) -> fused stage2(x)+colmax(w) -> finalize scales
// -> fused wave-per-row int8 quant (w then x) -> i8 MFMA GEMM
// (256x256 tile, BK=128, 8-phase pipeline with minimal waits: vmcnt only at
//  phases 2/4, mid-barrier only where a wait exists) + dequant epilogue.

typedef int v4i __attribute__((ext_vector_type(4)));

__device__ __forceinline__ void gld_lds16(const void* g, void* l) {
    __builtin_amdgcn_global_load_lds(
        (const __attribute__((address_space(1))) void*)g,
        (__attribute__((address_space(3))) void*)l,
        16, 0, 0);
}

// ---- column abs-max over a row range: out[k] = max_{r in [r0,r1)} |src[r][k]| ------
__device__ __forceinline__ void colmax_body(const float* __restrict__ src,
                                            int r0, int r1, int K,
                                            float* __restrict__ dst) {
    const int c = threadIdx.x * 4;          // 256 threads cover K=1024
    float m0 = 0.f, m1 = 0.f, m2 = 0.f, m3 = 0.f;
    const float* p = src + (size_t)r0 * K + c;
#pragma unroll 8
    for (int r = r0; r < r1; ++r, p += K) {
        float4 v = *(const float4*)p;
        m0 = fmaxf(m0, fabsf(v.x));
        m1 = fmaxf(m1, fabsf(v.y));
        m2 = fmaxf(m2, fabsf(v.z));
        m3 = fmaxf(m3, fabsf(v.w));
    }
    float4 o; o.x = m0; o.y = m1; o.z = m2; o.w = m3;
    *(float4*)(dst + c) = o;
}

// ---- stage-1 col abs-max of x: 512 blocks x 64 rows --------------------------------
__global__ __launch_bounds__(256) void colmax_part_kernel(const float* __restrict__ src,
                                                          int rows, int rpb, int K,
                                                          float* __restrict__ partial) {
    int r0 = blockIdx.x * rpb;
    int r1 = r0 + rpb; if (r1 > rows) r1 = rows;
    colmax_body(src, r0, r1, K, partial + (size_t)blockIdx.x * K);
}

// ---- fused stage-2: blocks [0,16) reduce x-partials -> p2x; [16,32) colmax(w) -> pw -
__global__ __launch_bounds__(256) void part2_fused_kernel(const float* __restrict__ p1x, int nx,
                                                          const float* __restrict__ w, int nw,
                                                          float* __restrict__ p2x,
                                                          float* __restrict__ pw, int K) {
    const int b = blockIdx.x;
    if (b < 16) {
        const int rpb = nx >> 4;
        colmax_body(p1x, b * rpb, (b + 1) * rpb, K, p2x + (size_t)b * K);
    } else {
        const int rpb = nw >> 4;
        colmax_body(w, (b - 16) * rpb, (b - 15) * rpb, K, pw + (size_t)(b - 16) * K);
    }
}

// ---- finalize: smooth = sqrt(max(mx*mw, eps)); inv = 1/smooth (IEEE) ----------------
__global__ void finalize_kernel(const float* __restrict__ px, int nx,
                                const float* __restrict__ pw, int nw,
                                float* __restrict__ smooth, float* __restrict__ inv_s, int K) {
    int c = blockIdx.x * blockDim.x + threadIdx.x;
    if (c >= K) return;
    float mx = 0.f, mw = 0.f;
    for (int r = 0; r < nx; ++r) mx = fmaxf(mx, px[(size_t)r * K + c]);
    for (int r = 0; r < nw; ++r) mw = fmaxf(mw, pw[(size_t)r * K + c]);
    float s = sqrtf(fmaxf(mx * mw, 1e-12f));
    smooth[c] = s;
    inv_s[c]  = 1.0f / s;
}

// ---- wave-per-row int8 quant body: 16 contiguous cols per lane, one dwordx4 store ---
__device__ __forceinline__ void quant_row_body(const float* __restrict__ src,
                                               const float* __restrict__ colscale,
                                               signed char* __restrict__ q,
                                               float* __restrict__ rowscale,
                                               int row, int K, int lane) {
    const float* srow = src + (size_t)row * K + lane * 16;
    const float* crow = colscale + lane * 16;
    float xs[16];
    float mv = 0.f;
#pragma unroll
    for (int i = 0; i < 4; ++i) {
        float4 v  = *(const float4*)(srow + i * 4);
        float4 cs = *(const float4*)(crow + i * 4);
        xs[i*4+0] = v.x * cs.x; xs[i*4+1] = v.y * cs.y;
        xs[i*4+2] = v.z * cs.z; xs[i*4+3] = v.w * cs.w;
        mv = fmaxf(mv, fmaxf(fmaxf(fabsf(xs[i*4+0]), fabsf(xs[i*4+1])),
                             fmaxf(fabsf(xs[i*4+2]), fabsf(xs[i*4+3]))));
    }
#pragma unroll
    for (int off = 32; off > 0; off >>= 1)
        mv = fmaxf(mv, __shfl_xor(mv, off, 64));
    const float rs = fmaxf(mv / 127.0f, 1e-12f);   // IEEE divide, matches numpy
    unsigned pk[4];
#pragma unroll
    for (int i = 0; i < 4; ++i) {
        float q0 = fminf(fmaxf(rintf(xs[i*4+0] / rs), -127.f), 127.f);  // IEEE divides
        float q1 = fminf(fmaxf(rintf(xs[i*4+1] / rs), -127.f), 127.f);
        float q2 = fminf(fmaxf(rintf(xs[i*4+2] / rs), -127.f), 127.f);
        float q3 = fminf(fmaxf(rintf(xs[i*4+3] / rs), -127.f), 127.f);
        int b0 = (int)q0, b1 = (int)q1, b2 = (int)q2, b3 = (int)q3;
        pk[i] = (unsigned)(b0 & 0xff) | ((unsigned)(b1 & 0xff) << 8)
              | ((unsigned)(b2 & 0xff) << 16) | ((unsigned)(b3 & 0xff) << 24);
    }
    *(uint4*)(q + (size_t)row * K + lane * 16) = make_uint4(pk[0], pk[1], pk[2], pk[3]);
    if (lane == 0) rowscale[row] = rs;
}

// ---- fused quant: blocks [0, N/4) quantize w; blocks [N/4, N/4+M/4) quantize x ------
__global__ __launch_bounds__(256) void quant_fused_kernel(
    const float* __restrict__ w, const float* __restrict__ x,
    const float* __restrict__ smooth, const float* __restrict__ inv_s,
    signed char* __restrict__ w_q, float* __restrict__ w_s,
    signed char* __restrict__ x_q, float* __restrict__ x_s,
    int K, int wblocks) {
    const int wave = threadIdx.x >> 6, lane = threadIdx.x & 63;
    const int b = blockIdx.x;
    if (b < wblocks) {
        quant_row_body(w, smooth, w_q, w_s, b * 4 + wave, K, lane);
    } else {
        quant_row_body(x, inv_s, x_q, x_s, (b - wblocks) * 4 + wave, K, lane);
    }
}

// ---- i8 GEMM: out[m,n] = i32acc * x_s[m] * w_s[n] + bias[n] -------------------------
// 256x256 tile, BK=128, 8 waves (2Mx4N, each 128x64 out), 8-phase counted-vmcnt
// pipeline, bank-free XOR-swizzled LDS, setprio around MFMA, XCD swizzle.
// Wait discipline (re-derived): phase p's ds_reads are protected by phase p-1's
// {vmcnt; barrier}. The only reads needing NEW completions are ph3 (ks1) and
// next-tile ph1 (ks0) -> vmcnt(8)+barrier at ph2 and ph4 ONLY. Phases 1/3 have
// no wait and no mid-barrier (their WAR hazard is sealed by the prior phase's
// end-barrier + per-wave lgkmcnt(0) before it). Steady queue: entering tile t,
// 8 outstanding [A(t,ks1),B(t,ks1),A(t+1,ks0),B(t+1,ks0)]; ph2 pops (t,ks1),
// ph4 pops (t+1,ks0) -- pop distance 6 phases (~1000 cyc).
__global__ __launch_bounds__(512, 2) void gemm_i8_kernel(
    const signed char* __restrict__ Aq,   // [M,K]
    const signed char* __restrict__ Bq,   // [N,K]
    const float* __restrict__ xs,         // [M]
    const float* __restrict__ wsc,        // [N]
    const float* __restrict__ bias,       // [N]
    float* __restrict__ out,              // [M,N] f32
    int M, int N, int K) {
    __shared__ __align__(16) signed char As[65536];   // [2][2][256*64]
    __shared__ __align__(16) signed char Bs[65536];

    const int tid  = threadIdx.x;
    const int lane = tid & 63;
    const int wave = tid >> 6;
    const int wm = wave >> 2;             // 0..1 -> rows wm*128..+127
    const int wn = wave & 3;              // 0..3 -> cols wn*64..+63
    const int g  = lane >> 4;             // 16B chunk within 64B kslice
    const int fr = lane & 15;

    const int NT = K >> 7;                // K/128 tiles (8 for K=1024)

    // XCD-aware bijective swizzle (grid % 8 == 0): each XCD gets contiguous wg chunk.
    const int nwg = gridDim.x;
    const int wg  = (blockIdx.x & 7) * (nwg >> 3) + (blockIdx.x >> 3);
    const int nTn = N >> 8;
    const int tm = wg / nTn, tn = wg % nTn;
    const int bm = tm << 8, bn = tn << 8;

    // staging: thread t -> LDS slot (row=t>>2, chunk=t&3); global chunk = chunk^((row>>1)&3)
    const int srow = tid >> 2;            // 0..127 (second load adds 128 rows, same (row>>1)&3)
    const int schk = (tid & 3) ^ ((tid >> 3) & 3);
    const signed char* srcA0 = Aq + (size_t)(bm + srow) * K + schk * 16;
    const signed char* srcA1 = srcA0 + (size_t)128 * K;
    const signed char* srcB0 = Bq + (size_t)(bn + srow) * K + schk * 16;
    const signed char* srcB1 = srcB0 + (size_t)128 * K;
    const int ldsSt = tid * 16;

    // fragment reads: row = base + fr (base%16==0), chunk g swizzled by (fr>>1)&3
    const int swz   = (g ^ ((fr >> 1) & 3)) * 16;
    const int aBase = (wm * 128 + fr) * 64 + swz;
    const int bBase = (wn * 64 + fr) * 64 + swz;

    v4i acc[8][4] = {};
    v4i bf[4];

#define STAGE_A(T, KS) do { \
        const int go_ = (T) * 128 + (KS) * 64; \
        signed char* l_ = &As[((T) & 1) * 32768 + (KS) * 16384 + ldsSt]; \
        gld_lds16(srcA0 + go_, l_); \
        gld_lds16(srcA1 + go_, l_ + 8192); \
    } while (0)
#define STAGE_B(T, KS) do { \
        const int go_ = (T) * 128 + (KS) * 64; \
        signed char* l_ = &Bs[((T) & 1) * 32768 + (KS) * 16384 + ldsSt]; \
        gld_lds16(srcB0 + go_, l_); \
        gld_lds16(srcB1 + go_, l_ + 8192); \
    } while (0)

// common phase body pieces
#define PH_READS(BUF, KS, MH) \
        const int hb_ = (BUF) * 32768 + (KS) * 16384; \
        v4i af[4]; \
        _Pragma("unroll") \
        for (int i = 0; i < 4; ++i) \
            af[i] = *(const v4i*)&As[hb_ + aBase + ((MH) * 4 + i) * 1024]; \
        if ((MH) == 0) { \
            _Pragma("unroll") \
            for (int j = 0; j < 4; ++j) \
                bf[j] = *(const v4i*)&Bs[hb_ + bBase + j * 1024]; \
        }

#define PH_MFMA(MH) \
        asm volatile("s_waitcnt lgkmcnt(0)" ::: "memory"); \
        __builtin_amdgcn_sched_barrier(0); \
        __builtin_amdgcn_s_setprio(1); \
        _Pragma("unroll") \
        for (int i = 0; i < 4; ++i) \
            _Pragma("unroll") \
            for (int j = 0; j < 4; ++j) \
                acc[(MH) * 4 + i][j] = __builtin_amdgcn_mfma_i32_16x16x64_i8( \
                    af[i], bf[j], acc[(MH) * 4 + i][j], 0, 0, 0); \
        __builtin_amdgcn_s_setprio(0); \
        asm volatile("s_barrier" ::: "memory");

// waiting phase: reads -> stage -> vmcnt -> barrier -> lgkm -> MFMA -> end barrier
#define PHASE_W(BUF, KS, MH, STG, WAIT) \
    do { \
        PH_READS(BUF, KS, MH) \
        STG; \
        asm volatile("s_waitcnt " WAIT ::: "memory"); \
        asm volatile("s_barrier" ::: "memory"); \
        PH_MFMA(MH) \
    } while (0)

// no-wait phase: reads -> stage -> lgkm -> MFMA -> end barrier (no mid sync)
#define PHASE_NW(BUF, KS, MH, STG) \
    do { \
        PH_READS(BUF, KS, MH) \
        STG; \
        PH_MFMA(MH) \
    } while (0)

    // prologue: tile0 complete + tile1 ks0 (6 halves, 12 loads); wait tile0 landed.
    STAGE_A(0, 0); STAGE_B(0, 0);
    STAGE_A(0, 1); STAGE_B(0, 1);
    STAGE_A(1, 0); STAGE_B(1, 0);
    asm volatile("s_waitcnt vmcnt(4)" ::: "memory");
    asm volatile("s_barrier" ::: "memory");

    // steady state (t = 0 .. NT-3): stage ks1(t+1) in ph1/ph2, ks0(t+2) in ph3/ph4.
    for (int t = 0; t < NT - 2; ++t) {
        const int buf = t & 1;
        PHASE_NW(buf, 0, 0, STAGE_A(t + 1, 1));
        PHASE_W (buf, 0, 1, STAGE_B(t + 1, 1), "vmcnt(8)");
        PHASE_NW(buf, 1, 0, STAGE_A(t + 2, 0));
        PHASE_W (buf, 1, 1, STAGE_B(t + 2, 0), "vmcnt(8)");
    }
    {   // tile NT-2: last ks1 staging; ph4 drains to 4 so ks0(NT-1) is landed.
        const int t = NT - 2, buf = t & 1;
        PHASE_NW(buf, 0, 0, STAGE_A(t + 1, 1));
        PHASE_W (buf, 0, 1, STAGE_B(t + 1, 1), "vmcnt(8)");
        PHASE_NW(buf, 1, 0, (void)0);
        PHASE_W (buf, 1, 1, (void)0, "vmcnt(4)");
    }
    {   // tile NT-1: ph2 drains remaining ks1(NT-1) before its ph3/ph4 reads.
        const int buf = (NT - 1) & 1;
        PHASE_NW(buf, 0, 0, (void)0);
        PHASE_W (buf, 0, 1, (void)0, "vmcnt(0)");
        PHASE_NW(buf, 1, 0, (void)0);
        PHASE_NW(buf, 1, 1, (void)0);
    }
#undef PHASE_W
#undef PHASE_NW
#undef PH_READS
#undef PH_MFMA
#undef STAGE_A
#undef STAGE_B

    // epilogue: C/D layout col=lane&15, row=(lane>>4)*4+reg (16x16 family)
    const int orow0 = bm + wm * 128 + g * 4;
    const int ocol0 = bn + wn * 64 + fr;
    float wv[4], bvv[4];
#pragma unroll
    for (int j = 0; j < 4; ++j) {
        wv[j]  = wsc[ocol0 + j * 16];
        bvv[j] = bias[ocol0 + j * 16];
    }
#pragma unroll
    for (int i = 0; i < 8; ++i) {
#pragma unroll
        for (int r = 0; r < 4; ++r) {
            const int row = orow0 + i * 16 + r;
            const float xv = xs[row];
            float* op = out + (size_t)row * N + ocol0;
#pragma unroll
            for (int j = 0; j < 4; ++j)
                op[j * 16] = (float)acc[i][j][r] * xv * wv[j] + bvv[j];
        }
    }
}

extern "C" void kernel_launch(void* const* d_in, const int* in_sizes, int n_in,
                              void* d_out, int out_size, void* d_ws, size_t ws_size,
                              hipStream_t stream) {
    const float* x    = (const float*)d_in[0];
    const float* w    = (const float*)d_in[1];
    const float* bias = (const float*)d_in[2];
    float* out = (float*)d_out;

    const int N = in_sizes[2];            // 1024
    const int K = in_sizes[1] / N;        // 1024
    const int M = in_sizes[0] / K;        // 32768

    char* ws = (char*)d_ws;
    float* p1x       = (float*)(ws);                    // 512 x K   (2 MB)
    float* p2x       = (float*)(ws + 2097152);          // 16 x K    (64 KB)
    float* pw        = (float*)(ws + 2162688);          // 16 x K    (64 KB)
    float* smooth    = (float*)(ws + 2228224);          // K
    float* inv_s     = (float*)(ws + 2232320);          // K
    float* w_s       = (float*)(ws + 2236416);          // N
    float* x_s       = (float*)(ws + 2240512);          // M  (128 KB)
    signed char* x_q = (signed char*)(ws + 2371584);    // M*K (32 MB)
    signed char* w_q = x_q + (size_t)M * K;             // N*K (1 MB)

    // stage-1 col abs-max of x: 512 blocks x 64 rows
    colmax_part_kernel<<<512, 256, 0, stream>>>(x, M, 64, K, p1x);
    // fused stage-2 (x partials) + col abs-max of w: 32 blocks
    part2_fused_kernel<<<32, 256, 0, stream>>>(p1x, 512, w, N, p2x, pw, K);
    // smooth scales
    finalize_kernel<<<(K + 255) / 256, 256, 0, stream>>>(p2x, 16, pw, 16, smooth, inv_s, K);
    // fused quant: w rows then x rows, one wave per row
    quant_fused_kernel<<<N / 4 + M / 4, 256, 0, stream>>>(w, x, smooth, inv_s,
                                                          w_q, w_s, x_q, x_s, K, N / 4);
    // GEMM: 256x256 tiles, 512 threads, grid = 128*4 = 512 (divisible by 8 XCDs)
    gemm_i8_kernel<<<(M / 256) * (N / 256), 512, 0, stream>>>(x_q, w_q, x_s, w_s, bias, out, M, N, K);
}